// Round 6
// baseline (57.066 us; speedup 1.0000x reference)
//
#include <hip/hip_runtime.h>
#include <math.h>

#define NH 16
#define LCACHE 4096

typedef __attribute__((ext_vector_type(8))) short short8;
typedef __attribute__((ext_vector_type(8))) unsigned short ushort8;
typedef __attribute__((ext_vector_type(4))) float f32x4;

__device__ __forceinline__ unsigned short f2bf(float f) {
    unsigned int u = __float_as_uint(f);
    u = (u + 0x7fffu + ((u >> 16) & 1u)) >> 16;   // RNE
    return (unsigned short)u;
}

// ---------------------------------------------------------------------------
// K1 prep, block-range specialized:
//  [0,256):   compress conv(s4,k4)+LN -> ck/cv f32 (each row once)
//  [256,512): pack w_attn[:, :1024] -> wq frags (LDS-staged coalesced)
//  [512,768): pack w_proj -> wp frags
//  [768,832): pack x -> xp A-frags
//  [832,840): out init = b_proj broadcast (for K2's atomic accumulation)
// Fragment-linear layout (1 KiB/frag): A f=(mt*16+kt)*4+kb*2+mb,
// B g=(nt*16+kt)*8+kb*4+nb; slot: lane l=(ke>>3)*16+r, j=ke&7.
// ---------------------------------------------------------------------------
__global__ __launch_bounds__(256)
void prep_kernel(const float* __restrict__ cached_k, const float* __restrict__ cached_v,
                 const float* __restrict__ kcw, const float* __restrict__ vcw,
                 const float* __restrict__ lkg, const float* __restrict__ lkb,
                 const float* __restrict__ lvg, const float* __restrict__ lvb,
                 const float* __restrict__ x, const float* __restrict__ w_attn,
                 const float* __restrict__ w_proj, const float* __restrict__ b_proj,
                 float* __restrict__ ck, float* __restrict__ cv,
                 ushort* __restrict__ xp, ushort* __restrict__ wq,
                 ushort* __restrict__ wp, float* __restrict__ out)
{
    __shared__ float Wt[64][65];
    const int bid = blockIdx.x, tid = threadIdx.x;
    const int w = tid >> 6, l = tid & 63;

    if (bid < 256) {
        // ---- compress ----
        const int bh = bid >> 1, T = bid & 1;
        const float* S = (T ? cached_v : cached_k) + (size_t)bh * (LCACHE * 64);
        const float* cwp = T ? vcw : kcw;
        float4 w4 = *(const float4*)(cwp + l * 4);
        float g = (T ? lvg : lkg)[l], bb = (T ? lvb : lkb)[l];
        float* dst = (T ? cv : ck) + (size_t)bh * 4096;
#pragma unroll
        for (int it = 0; it < 4; ++it) {
            float av[4];
#pragma unroll
            for (int q = 0; q < 4; ++q) {
                int lc = w * 16 + it * 4 + q;
                const float* p = S + (size_t)lc * 256 + l;
                float acc = p[0] * w4.x;
                acc = fmaf(p[64],  w4.y, acc);
                acc = fmaf(p[128], w4.z, acc);
                acc = fmaf(p[192], w4.w, acc);
                av[q] = acc;
            }
            float s1[4], s2[4];
#pragma unroll
            for (int q = 0; q < 4; ++q) { s1[q] = av[q]; s2[q] = av[q] * av[q]; }
#pragma unroll
            for (int o = 32; o; o >>= 1) {
#pragma unroll
                for (int q = 0; q < 4; ++q) {
                    s1[q] += __shfl_xor(s1[q], o);
                    s2[q] += __shfl_xor(s2[q], o);
                }
            }
#pragma unroll
            for (int q = 0; q < 4; ++q) {
                int lc = w * 16 + it * 4 + q;
                float mu  = s1[q] * 0.015625f;
                float var = s2[q] * 0.015625f - mu * mu;
                dst[(size_t)lc * 64 + l] = (av[q] - mu) * rsqrtf(var + 1e-5f) * g + bb;
            }
        }
        return;
    }

    if (bid < 768) {
        // ---- W pack via LDS staging ----
        const int isP = (bid >= 512);
        const int g2  = bid - (isP ? 512 : 256);
        const int nt = g2 >> 4, kt = g2 & 15;
        const float* W = isP ? w_proj : w_attn;
        const int ldw  = isP ? 1024 : 3072;
        ushort* D      = isP ? wp : wq;
#pragma unroll
        for (int rep = 0; rep < 16; ++rep) {
            int lin = rep * 256 + tid;
            int kr = lin >> 6, nn = lin & 63;
            Wt[kr][nn] = W[(size_t)(kt * 64 + kr) * ldw + nt * 64 + nn];
        }
        __syncthreads();
        int r = l & 15, kg8 = l >> 4;
#pragma unroll
        for (int e = 0; e < 2; ++e) {
            int bi = w + e * 4;
            int kb = bi >> 2, nb = bi & 3;
            ushort8 o;
#pragma unroll
            for (int j = 0; j < 8; ++j)
                o[j] = f2bf(Wt[kb * 32 + kg8 * 8 + j][nb * 16 + r]);
            size_t f_lin = (size_t)(nt * 16 + kt) * 8 + bi;
            *(ushort8*)(D + f_lin * 512 + l * 8) = o;
        }
        return;
    }

    if (bid < 832) {
        // ---- x pack ----
        int bid2 = bid - 768;
        int r = l & 15, kg8 = l >> 4;
#pragma unroll
        for (int i = 0; i < 4; ++i) {
            int f = bid2 * 16 + w * 4 + i;
            int mt = f >> 6, kt = (f >> 2) & 15, fi = f & 3;
            int kb = fi >> 1, mb = fi & 1;
            int m  = mt * 32 + mb * 16 + r;
            int k0 = kt * 64 + kb * 32 + kg8 * 8;
            const float* s = x + (size_t)m * 1024 + k0;
            ushort8 o;
#pragma unroll
            for (int j = 0; j < 8; ++j) o[j] = f2bf(s[j]);
            *(ushort8*)(xp + (size_t)f * 512 + l * 8) = o;
        }
        return;
    }

    // ---- out init: out[m][n] = b_proj[n] ----
    {
        int bid2 = bid - 832;                 // 0..7, 64 rows each
        const float4* bp4 = (const float4*)b_proj;
        float4* o4 = (float4*)out;
#pragma unroll
        for (int i = 0; i < 64; ++i) {
            int idx = i * 256 + tid;          // over 64 rows x 256 float4
            int row = bid2 * 64 + (idx >> 8), c4 = idx & 255;
            o4[(size_t)row * 256 + c4] = bp4[c4];
        }
    }
}

// ---------------------------------------------------------------------------
// K2 fused, per (b,h,half), 256 blocks x 512 thr (8 waves):
//  1. ck/cv reg-prefetch (issued first, lands under GEMM)
//  2. q-GEMM 32x64 K=1024: barrier-free, reg-direct frag loads,
//     wave = (kg, mb, nbp) specialization, split-K reduce in LDS
//  3. causal attention (fp32, LDS)
//  4. y -> LDS bf16 A-frags; out-projection contribution (K=64) reg-direct;
//     unsafeAtomicAdd into out (pre-initialized with b_proj).
// ---------------------------------------------------------------------------
__global__ __launch_bounds__(512)
void fused_kernel(const float* __restrict__ ck, const float* __restrict__ cv,
                  const float* __restrict__ b_attn,
                  const ushort* __restrict__ xp, const ushort* __restrict__ wq,
                  const ushort* __restrict__ wp, float* __restrict__ out)
{
    __shared__ float ck_s[64][65];
    __shared__ float cv_s[64][65];
    __shared__ float qs[32][68];
    __shared__ __align__(16) ushort y_lds[4 * 512];

    const int bid = blockIdx.x;
    const int h    = ((bid & 7) << 1) | ((bid >> 3) & 1);   // same h -> same XCD
    const int rem  = bid >> 4;
    const int b    = rem >> 1;
    const int half = rem & 1;
    const int mtA  = b * 2 + half;

    const int tid = threadIdx.x;
    const int w = tid >> 6, l = tid & 63;
    const int kg = w >> 2, mb = (w >> 1) & 1, nbp = w & 1;
    const int c = l & 15, rg = l >> 4;

    // 1. ck/cv prefetch (oldest loads; compiler waits before LDS write)
    const float4* ckg = (const float4*)(ck + (size_t)(b * NH + h) * 4096);
    const float4* cvg = (const float4*)(cv + (size_t)(b * NH + h) * 4096);
    float4 rk0 = ckg[tid], rk1 = ckg[tid + 512];
    float4 rv0 = cvg[tid], rv1 = cvg[tid + 512];

    // 2. q-GEMM: acc over this wave's (mb, nb = nbp*2 + {0,1})
    const ushort* ab = xp + (size_t)mtA * 32768 + mb * 512;
    const ushort* bb = wq + (size_t)h * 65536 + nbp * 1024;
    f32x4 acc0 = {0.f,0.f,0.f,0.f}, acc1 = {0.f,0.f,0.f,0.f};
#pragma unroll
    for (int s = 0; s < 8; ++s) {
        const int kt = kg * 8 + s;
        const ushort* A = ab + kt * 2048;
        const ushort* B = bb + kt * 4096;
        short8 a0  = *(const short8*)(A + l * 8);           // kb0
        short8 a1  = *(const short8*)(A + 1024 + l * 8);    // kb1
        short8 b00 = *(const short8*)(B + l * 8);           // kb0 nb_i0
        short8 b01 = *(const short8*)(B + 512 + l * 8);     // kb0 nb_i1
        short8 b10 = *(const short8*)(B + 2048 + l * 8);    // kb1 nb_i0
        short8 b11 = *(const short8*)(B + 2560 + l * 8);    // kb1 nb_i1
        acc0 = __builtin_amdgcn_mfma_f32_16x16x32_bf16(a0, b00, acc0, 0, 0, 0);
        acc1 = __builtin_amdgcn_mfma_f32_16x16x32_bf16(a0, b01, acc1, 0, 0, 0);
        acc0 = __builtin_amdgcn_mfma_f32_16x16x32_bf16(a1, b10, acc0, 0, 0, 0);
        acc1 = __builtin_amdgcn_mfma_f32_16x16x32_bf16(a1, b11, acc1, 0, 0, 0);
    }

    // ck/cv to LDS (2-way free on pad-65 reads later)
    {
        int row = tid >> 4, col = (tid & 15) * 4;
        ck_s[row][col] = rk0.x; ck_s[row][col+1] = rk0.y;
        ck_s[row][col+2] = rk0.z; ck_s[row][col+3] = rk0.w;
        ck_s[row+32][col] = rk1.x; ck_s[row+32][col+1] = rk1.y;
        ck_s[row+32][col+2] = rk1.z; ck_s[row+32][col+3] = rk1.w;
        cv_s[row][col] = rv0.x; cv_s[row][col+1] = rv0.y;
        cv_s[row][col+2] = rv0.z; cv_s[row][col+3] = rv0.w;
        cv_s[row+32][col] = rv1.x; cv_s[row+32][col+1] = rv1.y;
        cv_s[row+32][col+2] = rv1.z; cv_s[row+32][col+3] = rv1.w;
    }

    // split-K reduce: C/D row = rg*4+rr, col = c; n = nbp*32 + nb_i*16 + c
    {
        const int n0 = nbp * 32 + c;
        if (kg == 0) {
#pragma unroll
            for (int rr = 0; rr < 4; ++rr) {
                qs[mb * 16 + rg * 4 + rr][n0]      = acc0[rr];
                qs[mb * 16 + rg * 4 + rr][n0 + 16] = acc1[rr];
            }
        }
        __syncthreads();
        if (kg == 1) {
            float bv0 = b_attn[h * 64 + n0];
            float bv1 = b_attn[h * 64 + n0 + 16];
#pragma unroll
            for (int rr = 0; rr < 4; ++rr) {
                int m = mb * 16 + rg * 4 + rr;
                qs[m][n0]      = (qs[m][n0]      + acc0[rr] + bv0) * 0.125f;
                qs[m][n0 + 16] = (qs[m][n0 + 16] + acc1[rr] + bv1) * 0.125f;
            }
        }
        __syncthreads();
    }

    // 3. causal attention, 4 query rows per wave; y -> LDS bf16 A-frags
#pragma unroll
    for (int rr = 0; rr < 4; ++rr) {
        const int i  = w * 4 + rr;
        const int gq = half * 32 + i;
        float s = 0.f;
#pragma unroll
        for (int d = 0; d < 64; ++d)
            s = fmaf(qs[i][d], ck_s[l][d], s);
        bool valid = (l <= gq);
        s = valid ? s : -3.0e38f;
        float mx = s;
#pragma unroll
        for (int o = 32; o; o >>= 1) mx = fmaxf(mx, __shfl_xor(mx, o));
        float e = valid ? __expf(s - mx) : 0.f;
        float sum = e;
#pragma unroll
        for (int o = 32; o; o >>= 1) sum += __shfl_xor(sum, o);
        float p = e / sum;

        float a0 = 0.f, a1 = 0.f, a2 = 0.f, a3 = 0.f;
#pragma unroll
        for (int j = 0; j < 64; j += 4) {
            a0 = fmaf(__shfl(p, j + 0), cv_s[j + 0][l], a0);
            a1 = fmaf(__shfl(p, j + 1), cv_s[j + 1][l], a1);
            a2 = fmaf(__shfl(p, j + 2), cv_s[j + 2][l], a2);
            a3 = fmaf(__shfl(p, j + 3), cv_s[j + 3][l], a3);
        }
        float acc = (a0 + a1) + (a2 + a3);

        int mb2 = i >> 4, r15 = i & 15;
        int kb  = l >> 5, ke = l & 31;
        int l2  = ((ke >> 3) << 4) | r15;
        int j2  = ke & 7;
        y_lds[(kb * 2 + mb2) * 512 + l2 * 8 + j2] = f2bf(acc);
    }
    __syncthreads();

    // 4. out-projection: wave handles cols [w*128, w*128+128), K=64 (this head)
    {
        short8 ya[2][2];    // [mb2][kb]
#pragma unroll
        for (int m2 = 0; m2 < 2; ++m2)
#pragma unroll
            for (int kb = 0; kb < 2; ++kb)
                ya[m2][kb] = *(const short8*)&y_lds[(kb * 2 + m2) * 512 + l * 8];

        f32x4 pacc[2][4][2];    // [nt_i][nb][mb2] — all indices compile-time
#pragma unroll
        for (int nt_i = 0; nt_i < 2; ++nt_i) {
            const int nt = w * 2 + nt_i;
            const ushort* base = wp + (size_t)(nt * 16 + h) * 4096;
#pragma unroll
            for (int nb = 0; nb < 4; ++nb) {
                short8 b0 = *(const short8*)(base + nb * 512 + l * 8);          // kb0
                short8 b1 = *(const short8*)(base + 2048 + nb * 512 + l * 8);   // kb1
#pragma unroll
                for (int m2 = 0; m2 < 2; ++m2) {
                    f32x4 t = {0.f, 0.f, 0.f, 0.f};
                    t = __builtin_amdgcn_mfma_f32_16x16x32_bf16(ya[m2][0], b0, t, 0, 0, 0);
                    t = __builtin_amdgcn_mfma_f32_16x16x32_bf16(ya[m2][1], b1, t, 0, 0, 0);
                    pacc[nt_i][nb][m2] = t;
                }
            }
        }
#pragma unroll
        for (int nt_i = 0; nt_i < 2; ++nt_i)
#pragma unroll
            for (int nb = 0; nb < 4; ++nb)
#pragma unroll
                for (int m2 = 0; m2 < 2; ++m2)
#pragma unroll
                    for (int rr = 0; rr < 4; ++rr) {
                        int m  = mtA * 32 + m2 * 16 + rg * 4 + rr;
                        int nn = (w * 2 + nt_i) * 64 + nb * 16 + c;
                        unsafeAtomicAdd(&out[(size_t)m * 1024 + nn],
                                        pacc[nt_i][nb][m2][rr]);
                    }
    }
}

// ---------------------------------------------------------------------------
extern "C" void kernel_launch(void* const* d_in, const int* in_sizes, int n_in,
                              void* d_out, int out_size, void* d_ws, size_t ws_size,
                              hipStream_t stream)
{
    const float* x        = (const float*)d_in[0];
    const float* cached_k = (const float*)d_in[1];
    const float* cached_v = (const float*)d_in[2];
    const float* w_attn   = (const float*)d_in[3];
    const float* b_attn   = (const float*)d_in[4];
    const float* w_proj   = (const float*)d_in[5];
    const float* b_proj   = (const float*)d_in[6];
    const float* k_conv   = (const float*)d_in[7];
    const float* v_conv   = (const float*)d_in[8];
    const float* ln_k_g   = (const float*)d_in[9];
    const float* ln_k_b   = (const float*)d_in[10];
    const float* ln_v_g   = (const float*)d_in[11];
    const float* ln_v_b   = (const float*)d_in[12];

    ushort* xp = (ushort*)d_ws;            // 524288 u16
    ushort* wq = xp + 524288;              // 1048576 u16
    ushort* wp = wq + 1048576;             // 1048576 u16
    float*  ck = (float*)(wp + 1048576);   // 524288 f32
    float*  cv = ck + 524288;              // 524288 f32
    float*  out = (float*)d_out;

    prep_kernel<<<840, 256, 0, stream>>>(cached_k, cached_v, k_conv, v_conv,
                                         ln_k_g, ln_k_b, ln_v_g, ln_v_b,
                                         x, w_attn, w_proj, b_proj,
                                         ck, cv, xp, wq, wp, out);
    fused_kernel<<<256, 512, 0, stream>>>(ck, cv, b_attn, xp, wq, wp, out);
}